// Round 4
// baseline (2462.016 us; speedup 1.0000x reference)
//
#include <hip/hip_runtime.h>
#include <math.h>

// Sinkhorn loss, B=8, S=2048, P=1024, D=2, eps=0.01, 50 iters.
// PERSISTENT-KERNEL v4 — register-blocked LSE.
// R3 (1918us, VALUBusy 17%, 1 wave/SIMD, 8.3M LDS-conflict cycles) showed the
// old inner loop is LDS-BW + latency bound: one row per 16B LDS read => each
// wave re-reads the whole tile 8x, and 212 VGPR x 256thr x 49.5KB LDS gave
// zero latency hiding. v4: each lane holds 8 f-rows / 4 g-cols in registers
// per LDS read (8x/4x LDS traffic cut), consecutive-lane addressing
// (conflict-free), full 64-lane butterfly LSE, 512 threads (2 waves/SIMD).
// Grid stays 256 blocks = 1/CU (geometry-guaranteed co-residency, proven R3).
// Base-2 scaled potentials: F2 = f/(eps*ln2), G2 = g/(eps*ln2), K = 100*log2(e)
//   f elem: u = 2K*x.y + (G2[p] - K*y2[p]);  F2 = (K*x2 - log2 S) - LSE2(u)
//   g elem: u = 2K*x.y + (F2[s] - K*x2[s]);  G2 = (K*y2 + logb2) - LSE2(u)

#define BB 8
#define SS 2048
#define PP 1024
#define NEG_INF -1e9f
#define LOG2S 11.0f
#define ITERS 50
#define K2E 144.269504088896f   /* 100*log2(e) */
#define TWOK 288.539008177792f  /* 200*log2(e) */
#define NBLK 256
#define BLK_PER_BATCH 32

__device__ __forceinline__ float fexp2(float x) {
  return __builtin_amdgcn_exp2f(x);
}
__device__ __forceinline__ float flog2(float x) {
  return __builtin_amdgcn_logf(x);
}

// agent-scope coherent (cache-bypassing) accessors for cross-XCD data
__device__ __forceinline__ float coh_load(const float* p) {
  return __hip_atomic_load((float*)p, __ATOMIC_RELAXED, __HIP_MEMORY_SCOPE_AGENT);
}
__device__ __forceinline__ void coh_store(float* p, float v) {
  __hip_atomic_store(p, v, __ATOMIC_RELAXED, __HIP_MEMORY_SCOPE_AGENT);
}

// 32-block per-batch barrier; target is monotonic (32 * phase_number).
__device__ __forceinline__ void batch_barrier(int* cnt, int target) {
  __syncthreads();  // all waves drain their stores (vmcnt0) before arrival
  if (threadIdx.x == 0) {
    __hip_atomic_fetch_add(cnt, 1, __ATOMIC_RELEASE, __HIP_MEMORY_SCOPE_AGENT);
    while (__hip_atomic_load(cnt, __ATOMIC_ACQUIRE, __HIP_MEMORY_SCOPE_AGENT) <
           target)
      __builtin_amdgcn_s_sleep(2);
  }
  __syncthreads();
  __builtin_amdgcn_fence(__ATOMIC_ACQUIRE, "agent");
}

// ws layout (bytes):
//   G2    : [0,      32768)   B*P float
//   F2    : [32768,  98304)   B*S float
//   logb2 : [98304, 131072)   B*P float
//   cnt   : [131072, 135168)  8 batch counters, stride 32 ints (128 B)

__global__ __launch_bounds__(1024) void setup_kernel(
    const int* __restrict__ labels, float* __restrict__ G2,
    float* __restrict__ logb2, int* __restrict__ cnt,
    float* __restrict__ out) {
  __shared__ int c[PP];
  int b = blockIdx.x;
  int t = threadIdx.x;  // 1024 threads
  c[t] = 0;
  __syncthreads();
  atomicAdd(&c[labels[b * SS + t] & (PP - 1)], 1);
  atomicAdd(&c[labels[b * SS + PP + t] & (PP - 1)], 1);
  __syncthreads();
  int cc = c[t];
  logb2[b * PP + t] = (cc > 0) ? (flog2((float)cc) - LOG2S) : NEG_INF;
  G2[b * PP + t] = 0.0f;
  if (t == 0) {
    cnt[b << 5] = 0;
    if (b == 0) out[0] = 0.0f;
  }
}

__global__ __launch_bounds__(512, 2) void sinkhorn_persist(
    const float* __restrict__ preds, const float* __restrict__ pos,
    const float* __restrict__ logb2, float* __restrict__ F2g,
    float* __restrict__ G2g, int* __restrict__ cnt, float* __restrict__ out) {
  __shared__ float4 shf[1032];  // (y0, y1, qy = G2 - K*y2, pad), +16B pad /128
  __shared__ float4 shg[2064];  // (x0, x1, qx = F2 - K*x2, pad), +16B pad /128
  __shared__ float spart;
  const int t = threadIdx.x;    // 512 threads, 8 waves
  const int blk = blockIdx.x;   // 256 blocks = 1/CU
  const int bb = blk >> 5;      // 32 blocks per batch
  int* mycnt = cnt + (bb << 5);
  const float2* pos2 = (const float2*)pos;
  const float2* preds2 = (const float2*)preds;
  float* G2b = G2g + (bb << 10);
  float* F2b = F2g + (bb << 11);

  // ---- persistent init: x/y constants into LDS + K-scaled norms in regs
  float yr2[2], xr2[4];
#pragma unroll
  for (int k = 0; k < 2; ++k) {
    int e = t + (k << 9);
    float2 y = pos2[(bb << 10) + e];
    yr2[k] = y.x * y.x + y.y * y.y;
    shf[e + (e >> 7)] = make_float4(y.x, y.y, 0.0f, 0.0f);
  }
#pragma unroll
  for (int k = 0; k < 4; ++k) {
    int e = t + (k << 9);
    float2 x = preds2[(bb << 11) + e];
    xr2[k] = x.x * x.x + x.y * x.y;
    shg[e + (e >> 7)] = make_float4(x.x, x.y, 0.0f, 0.0f);
  }

  const int w = t >> 6, lane = t & 63;
  // f-phase: wave w owns 8 rows [blk*64 + w*8, +8); lane covers 16 cols
  const int frowb = (blk << 6) + (w << 3);
  float fk0[8], fk1[8], fc0[8];
#pragma unroll
  for (int r = 0; r < 8; ++r) {
    float2 fx = preds2[frowb + r];  // wave-uniform broadcast load
    fk0[r] = TWOK * fx.x;
    fk1[r] = TWOK * fx.y;
    fc0[r] = fmaf(K2E, fx.x * fx.x + fx.y * fx.y, -LOG2S);
  }
  // g-phase: wave w owns 4 cols [blk*32 + w*4, +4); lane covers 32 rows
  const int gcolb = (blk << 5) + (w << 2);
  float gk0[4], gk1[4], gc0[4];
#pragma unroll
  for (int c = 0; c < 4; ++c) {
    float2 gy = pos2[gcolb + c];
    gk0[c] = TWOK * gy.x;
    gk1[c] = TWOK * gy.y;
    gc0[c] = fmaf(K2E, gy.x * gy.x + gy.y * gy.y, logb2[gcolb + c]);
  }

  float u[128];  // shared storage: f uses u[r*16+i], g uses u[c*32+j]
  int target = 0;

  for (int it = 0; it < ITERS; ++it) {
    // ---- stage qy = G2 - K*y2 (4KB coherent reads; same-thread LDS slots)
#pragma unroll
    for (int k = 0; k < 2; ++k) {
      int e = t + (k << 9);
      shf[e + (e >> 7)].z = fmaf(-K2E, yr2[k], coh_load(&G2b[e]));
    }
    __syncthreads();
    // ---- f-compute: 8 rows/lane in regs, one 16B LDS read feeds 8 rows
    {
      float m[8], s[8];
#pragma unroll
      for (int r = 0; r < 8; ++r) m[r] = -3.4e38f;
#pragma unroll
      for (int i = 0; i < 16; ++i) {
        int e = (i << 6) + lane;          // consecutive-lane: conflict-free
        float4 a = shf[e + (e >> 7)];
#pragma unroll
        for (int r = 0; r < 8; ++r) {
          float uu = fmaf(fk0[r], a.x, fmaf(fk1[r], a.y, a.z));
          u[r * 16 + i] = uu;
          m[r] = fmaxf(m[r], uu);
        }
      }
#pragma unroll
      for (int off = 1; off <= 32; off <<= 1)
#pragma unroll
        for (int r = 0; r < 8; ++r) m[r] = fmaxf(m[r], __shfl_xor(m[r], off, 64));
#pragma unroll
      for (int r = 0; r < 8; ++r) s[r] = 0.0f;
#pragma unroll
      for (int i = 0; i < 16; ++i)
#pragma unroll
        for (int r = 0; r < 8; ++r) s[r] += fexp2(u[r * 16 + i] - m[r]);
#pragma unroll
      for (int off = 1; off <= 32; off <<= 1)
#pragma unroll
        for (int r = 0; r < 8; ++r) s[r] += __shfl_xor(s[r], off, 64);
      if (lane == 0) {
#pragma unroll
        for (int r = 0; r < 8; ++r)
          coh_store(&F2g[frowb + r], fc0[r] - m[r] - flog2(s[r]));
      }
    }
    target += BLK_PER_BATCH;
    batch_barrier(mycnt, target);

    // ---- stage qx = F2 - K*x2 (8KB coherent reads)
#pragma unroll
    for (int k = 0; k < 4; ++k) {
      int e = t + (k << 9);
      shg[e + (e >> 7)].z = fmaf(-K2E, xr2[k], coh_load(&F2b[e]));
    }
    __syncthreads();
    // ---- g-compute: 4 cols/lane in regs, one 16B LDS read feeds 4 cols
    {
      float m[4], s[4];
#pragma unroll
      for (int c = 0; c < 4; ++c) m[c] = -3.4e38f;
#pragma unroll
      for (int j = 0; j < 32; ++j) {
        int e = (j << 6) + lane;
        float4 a = shg[e + (e >> 7)];
#pragma unroll
        for (int c = 0; c < 4; ++c) {
          float uu = fmaf(gk0[c], a.x, fmaf(gk1[c], a.y, a.z));
          u[c * 32 + j] = uu;
          m[c] = fmaxf(m[c], uu);
        }
      }
#pragma unroll
      for (int off = 1; off <= 32; off <<= 1)
#pragma unroll
        for (int c = 0; c < 4; ++c) m[c] = fmaxf(m[c], __shfl_xor(m[c], off, 64));
#pragma unroll
      for (int c = 0; c < 4; ++c) s[c] = 0.0f;
#pragma unroll
      for (int j = 0; j < 32; ++j)
#pragma unroll
        for (int c = 0; c < 4; ++c) s[c] += fexp2(u[c * 32 + j] - m[c]);
#pragma unroll
      for (int off = 1; off <= 32; off <<= 1)
#pragma unroll
        for (int c = 0; c < 4; ++c) s[c] += __shfl_xor(s[c], off, 64);
      if (lane == 0) {
#pragma unroll
        for (int c = 0; c < 4; ++c)
          coh_store(&G2g[gcolb + c], gc0[c] - m[c] - flog2(s[c]));
      }
    }
    target += BLK_PER_BATCH;
    batch_barrier(mycnt, target);
  }

  // ---- fused final: restage qy with final G2, rowsum over own 64 rows
  if (t == 0) spart = 0.0f;
#pragma unroll
  for (int k = 0; k < 2; ++k) {
    int e = t + (k << 9);
    shf[e + (e >> 7)].z = fmaf(-K2E, yr2[k], coh_load(&G2b[e]));
  }
  __syncthreads();
  float acc = 0.0f;
#pragma unroll
  for (int rr = 0; rr < 8; ++rr) {
    int row = frowb + rr;
    float2 x = preds2[row];
    float x2 = x.x * x.x + x.y * x.y;
    float qx = fmaf(-K2E, x2, coh_load(&F2g[row]));
#pragma unroll
    for (int i = 0; i < 16; ++i) {
      int p = (i << 6) + lane;
      float4 a = shf[p + (p >> 7)];
      float y2 = fmaf(a.x, a.x, a.y * a.y);
      float tt = fmaf(x.y, a.y, x.x * a.x);
      float c = fmaxf(x2 + y2 - 2.0f * tt, 0.0f);  // clamped cost
      float v2 = fmaf(TWOK, tt, a.z + qx);         // -K*C' + F2 + G2 (base-2)
      acc = fmaf(fexp2(v2), c, acc);               // c==0 kills C'<0 case
    }
  }
#pragma unroll
  for (int off = 32; off; off >>= 1) acc += __shfl_xor(acc, off, 64);
  if (lane == 0) atomicAdd(&spart, acc);
  __syncthreads();
  if (t == 0) atomicAdd(out, spart * (1.0f / (float)BB));
}

extern "C" void kernel_launch(void* const* d_in, const int* in_sizes, int n_in,
                              void* d_out, int out_size, void* d_ws,
                              size_t ws_size, hipStream_t stream) {
  const float* preds = (const float*)d_in[0];  // [B,S,2]
  const int* labels = (const int*)d_in[1];     // [B,S]
  const float* pos = (const float*)d_in[2];    // [B,P,2]
  float* out = (float*)d_out;
  char* ws = (char*)d_ws;
  float* G2 = (float*)(ws);
  float* F2 = (float*)(ws + 32768);
  float* logb2 = (float*)(ws + 98304);
  int* cnt = (int*)(ws + 131072);

  hipLaunchKernelGGL(setup_kernel, dim3(BB), dim3(1024), 0, stream, labels, G2,
                     logb2, cnt, out);
  hipLaunchKernelGGL(sinkhorn_persist, dim3(NBLK), dim3(512), 0, stream,
                     preds, pos, logb2, F2, G2, cnt, out);
}